// Round 1
// baseline (622.981 us; speedup 1.0000x reference)
//
#include <hip/hip_runtime.h>
#include <hip/hip_bf16.h>

typedef __attribute__((ext_vector_type(8))) short bf16x8;
typedef __attribute__((ext_vector_type(4))) float f32x4;
typedef __attribute__((ext_vector_type(4))) short short4v;

__device__ __forceinline__ unsigned short f2bf(float f) {
  union { float f; unsigned u; } x; x.f = f;
  return (unsigned short)((x.u + 0x7FFFu + ((x.u >> 16) & 1u)) >> 16);
}

__device__ __forceinline__ void lds_cp16(const void* g, void* l) {
  __builtin_amdgcn_global_load_lds(
      (const __attribute__((address_space(1))) void*)g,
      (__attribute__((address_space(3))) void*)l,
      16, 0, 0);
}

// ---------------- cast fp32 -> bf16, vectorized ----------------
__global__ __launch_bounds__(256) void cast_x(const float* __restrict__ in,
                                              short* __restrict__ out, int n4) {
  int i = blockIdx.x * 256 + threadIdx.x;
  if (i >= n4) return;
  float4 v = reinterpret_cast<const float4*>(in)[i];
  short4v o;
  o.x = (short)f2bf(v.x); o.y = (short)f2bf(v.y);
  o.z = (short)f2bf(v.z); o.w = (short)f2bf(v.w);
  reinterpret_cast<short4v*>(out)[i] = o;
}

// ---------------- transpose + cast: in KxN fp32 -> out NxK bf16 ----------------
__global__ __launch_bounds__(256) void transp_cast(const float* __restrict__ in,
                                                   short* __restrict__ out,
                                                   int K, int N) {
  __shared__ float t[32][33];
  int bn = blockIdx.x * 32, bk = blockIdx.y * 32;
  int tx = threadIdx.x, ty = threadIdx.y;
  for (int i = ty; i < 32; i += 8)
    t[i][tx] = in[(size_t)(bk + i) * N + bn + tx];
  __syncthreads();
  for (int i = ty; i < 32; i += 8)
    out[(size_t)(bn + i) * K + bk + tx] = (short)f2bf(t[tx][i]);
}

// ---------------- GEMM: A (MxK bf16 rowmajor) @ Bt^T (Bt is NxK bf16 rowmajor)
// EPI=0: write fp32 C (MxN). EPI=1: fused RoPE epilogue -> Q/K/V bf16 head-major.
template <int EPI>
__global__ __launch_bounds__(256) void gemm_bf16(
    const short* __restrict__ A, const short* __restrict__ Bt,
    float* __restrict__ C,
    short* __restrict__ Qo, short* __restrict__ Ko, short* __restrict__ Vo,
    const float* __restrict__ cosT, const float* __restrict__ sinT,
    int M, int N, int K) {
  __shared__ __align__(16) short As[128 * 32];
  __shared__ __align__(16) short Bs[128 * 32];
  const int tid = threadIdx.x;
  const int w = tid >> 6, l = tid & 63;
  const int l15 = l & 15, l4 = l >> 4;
  const int m0 = blockIdx.x * 128, n0 = blockIdx.y * 128;

  f32x4 acc[2][8];
#pragma unroll
  for (int i = 0; i < 2; i++)
#pragma unroll
    for (int j = 0; j < 8; j++) acc[i][j] = (f32x4){0.f, 0.f, 0.f, 0.f};

  const int cA = w * 128 + l;  // 16B-chunk id; chunk c -> row c>>2, byte (c&3)*16
  for (int k0 = 0; k0 < K; k0 += 32) {
    __syncthreads();
    {
      const char* g0 = (const char*)(A + (size_t)(m0 + (cA >> 2)) * K + k0) + (cA & 3) * 16;
      const char* g1 = (const char*)(A + (size_t)(m0 + (cA >> 2) + 16) * K + k0) + (cA & 3) * 16;
      lds_cp16(g0, (char*)As + w * 2048);
      lds_cp16(g1, (char*)As + w * 2048 + 1024);
      const char* h0 = (const char*)(Bt + (size_t)(n0 + (cA >> 2)) * K + k0) + (cA & 3) * 16;
      const char* h1 = (const char*)(Bt + (size_t)(n0 + (cA >> 2) + 16) * K + k0) + (cA & 3) * 16;
      lds_cp16(h0, (char*)Bs + w * 2048);
      lds_cp16(h1, (char*)Bs + w * 2048 + 1024);
    }
    __syncthreads();
    bf16x8 a[2], b[8];
#pragma unroll
    for (int mi = 0; mi < 2; mi++)
      a[mi] = *(const bf16x8*)(As + (w * 32 + mi * 16 + l15) * 32 + l4 * 8);
#pragma unroll
    for (int ni = 0; ni < 8; ni++)
      b[ni] = *(const bf16x8*)(Bs + (ni * 16 + l15) * 32 + l4 * 8);
#pragma unroll
    for (int mi = 0; mi < 2; mi++)
#pragma unroll
      for (int ni = 0; ni < 8; ni++)
        acc[mi][ni] = __builtin_amdgcn_mfma_f32_16x16x32_bf16(a[mi], b[ni], acc[mi][ni], 0, 0, 0);
  }

  if (EPI == 0) {
#pragma unroll
    for (int mi = 0; mi < 2; mi++) {
      int row0 = m0 + w * 32 + mi * 16 + l4 * 4;
#pragma unroll
      for (int ni = 0; ni < 8; ni++) {
        int col = n0 + ni * 16 + l15;
#pragma unroll
        for (int r = 0; r < 4; r++)
          C[(size_t)(row0 + r) * N + col] = acc[mi][ni][r];
      }
    }
  } else {
    const int bn = blockIdx.y;  // one 128-wide head column per n-tile
#pragma unroll
    for (int mi = 0; mi < 2; mi++) {
#pragma unroll
      for (int r = 0; r < 4; r++) {
        int grow = m0 + w * 32 + mi * 16 + l4 * 4 + r;
        int bb = grow >> 11, pos = grow & 2047;
        if (bn < 20) {
          float c4[4], s4[4];
#pragma unroll
          for (int ni = 0; ni < 4; ni++) {
            int dh = ni * 16 + l15;  // < 64; cos/sin identical at dh and dh+64
            c4[ni] = cosT[pos * 128 + dh];
            s4[ni] = sinT[pos * 128 + dh];
          }
          short* dst;
          if (bn < 16) dst = Qo + ((size_t)(bb * 16 + bn) * 2048 + pos) * 128;
          else         dst = Ko + ((size_t)(bb * 4 + (bn - 16)) * 2048 + pos) * 128;
#pragma unroll
          for (int ni = 0; ni < 4; ni++) {
            int dh = ni * 16 + l15;
            float xlo = acc[mi][ni][r], xhi = acc[mi][ni + 4][r];
            dst[dh]      = (short)f2bf(xlo * c4[ni] - xhi * s4[ni]);
            dst[dh + 64] = (short)f2bf(xhi * c4[ni] + xlo * s4[ni]);
          }
        } else {
          short* dst = Vo + ((size_t)(bb * 4 + (bn - 20)) * 2048 + pos) * 128;
#pragma unroll
          for (int ni = 0; ni < 8; ni++)
            dst[ni * 16 + l15] = (short)f2bf(acc[mi][ni][r]);
        }
      }
    }
  }
}

// ---------------- flash attention, causal, GQA ----------------
// grid: (L/64, B*H); 4 waves/block, 16 q-rows per wave, KVBLK=32
__global__ __launch_bounds__(256) void attn_fwd(
    const short* __restrict__ Q, const short* __restrict__ K,
    const short* __restrict__ V, short* __restrict__ AO) {
  __shared__ __align__(16) short Vt[128 * 32];       // V^T tile [dh][key]
  __shared__ __align__(16) short Pl[4][16 * 32];     // per-wave P staging
  const int tid = threadIdx.x;
  const int w = tid >> 6, l = tid & 63;
  const int l15 = l & 15, l4 = l >> 4;
  const int qt = blockIdx.x, bh = blockIdx.y;
  const int b = bh >> 4, h = bh & 15, kv = h >> 2;
  const int q0w = qt * 64 + w * 16;
  const short* Qbase = Q + (size_t)(b * 16 + h) * 2048 * 128;
  const short* Kbase = K + (size_t)(b * 4 + kv) * 2048 * 128;
  const short* Vbase = V + (size_t)(b * 4 + kv) * 2048 * 128;

  bf16x8 qf[4];
#pragma unroll
  for (int kb = 0; kb < 4; kb++)
    qf[kb] = *(const bf16x8*)(Qbase + (size_t)(q0w + l15) * 128 + kb * 32 + l4 * 8);

  f32x4 oacc[8];
#pragma unroll
  for (int i = 0; i < 8; i++) oacc[i] = (f32x4){0.f, 0.f, 0.f, 0.f};
  float mrow[4] = {-1e30f, -1e30f, -1e30f, -1e30f};
  float lrow[4] = {0.f, 0.f, 0.f, 0.f};

  const int ntiles = 2 * qt + 2;
  for (int nt = 0; nt < ntiles; nt++) {
    const int k0 = nt * 32;
    __syncthreads();
    // stage V^T (32 keys x 128 dh -> [128][32])
#pragma unroll
    for (int i = 0; i < 2; i++) {
      int c = tid + i * 256;
      int key = c >> 4, dh0 = (c & 15) * 8;
      bf16x8 v = *(const bf16x8*)(Vbase + (size_t)(k0 + key) * 128 + dh0);
#pragma unroll
      for (int j = 0; j < 8; j++) Vt[(dh0 + j) * 32 + key] = v[j];
    }
    __syncthreads();

    // S = Q @ K^T  (16 q x 32 keys per wave)
    f32x4 sa[2];
    sa[0] = (f32x4){0.f, 0.f, 0.f, 0.f};
    sa[1] = (f32x4){0.f, 0.f, 0.f, 0.f};
#pragma unroll
    for (int kg = 0; kg < 2; kg++)
#pragma unroll
      for (int kb = 0; kb < 4; kb++) {
        bf16x8 kf = *(const bf16x8*)(Kbase + (size_t)(k0 + kg * 16 + l15) * 128 + kb * 32 + l4 * 8);
        sa[kg] = __builtin_amdgcn_mfma_f32_16x16x32_bf16(qf[kb], kf, sa[kg], 0, 0, 0);
      }

    // online softmax; C-layout row = l4*4+r, col(key) = kg*16+l15
    const float sc_s = 0.08838834764831845f;   // 1/sqrt(128)
    const float LOG2E = 1.4426950408889634f;
    float p[2][4], tilem[4];
#pragma unroll
    for (int r = 0; r < 4; r++) {
      int qrow = q0w + l4 * 4 + r;
      float s0 = sa[0][r] * sc_s; if (k0 + l15 > qrow)      s0 = -1e30f;
      float s1 = sa[1][r] * sc_s; if (k0 + 16 + l15 > qrow) s1 = -1e30f;
      p[0][r] = s0; p[1][r] = s1;
      float t = fmaxf(s0, s1);
      t = fmaxf(t, __shfl_xor(t, 1));
      t = fmaxf(t, __shfl_xor(t, 2));
      t = fmaxf(t, __shfl_xor(t, 4));
      t = fmaxf(t, __shfl_xor(t, 8));
      tilem[r] = t;
    }
#pragma unroll
    for (int r = 0; r < 4; r++) {
      float newm = fmaxf(mrow[r], tilem[r]);
      float scal = exp2f((mrow[r] - newm) * LOG2E);
      mrow[r] = newm;
      float p0 = exp2f((p[0][r] - newm) * LOG2E);
      float p1 = exp2f((p[1][r] - newm) * LOG2E);
      p[0][r] = p0; p[1][r] = p1;
      float ts = p0 + p1;
      ts += __shfl_xor(ts, 1);
      ts += __shfl_xor(ts, 2);
      ts += __shfl_xor(ts, 4);
      ts += __shfl_xor(ts, 8);
      lrow[r] = lrow[r] * scal + ts;
#pragma unroll
      for (int nb = 0; nb < 8; nb++) oacc[nb][r] *= scal;
    }

    // P: C-layout -> A-layout via per-wave LDS
#pragma unroll
    for (int r = 0; r < 4; r++) {
      Pl[w][(l4 * 4 + r) * 32 + l15]      = (short)f2bf(p[0][r]);
      Pl[w][(l4 * 4 + r) * 32 + 16 + l15] = (short)f2bf(p[1][r]);
    }
    asm volatile("s_waitcnt lgkmcnt(0)" ::: "memory");
    bf16x8 pf = *(const bf16x8*)(&Pl[w][l15 * 32 + l4 * 8]);
#pragma unroll
    for (int nb = 0; nb < 8; nb++) {
      bf16x8 vf = *(const bf16x8*)(Vt + (nb * 16 + l15) * 32 + l4 * 8);
      oacc[nb] = __builtin_amdgcn_mfma_f32_16x16x32_bf16(pf, vf, oacc[nb], 0, 0, 0);
    }
  }

  // epilogue: normalize, write bf16 AO [B][L][H*Dh]
#pragma unroll
  for (int r = 0; r < 4; r++) {
    float inv = 1.0f / lrow[r];
    size_t rowb = ((size_t)b * 2048 + q0w + l4 * 4 + r) * 2048 + h * 128;
#pragma unroll
    for (int nb = 0; nb < 8; nb++)
      AO[rowb + nb * 16 + l15] = (short)f2bf(oacc[nb][r] * inv);
  }
}

extern "C" void kernel_launch(void* const* d_in, const int* in_sizes, int n_in,
                              void* d_out, int out_size, void* d_ws, size_t ws_size,
                              hipStream_t stream) {
  const float* hs   = (const float*)d_in[0];
  const float* cosT = (const float*)d_in[1];
  const float* sinT = (const float*)d_in[2];
  const float* Wq   = (const float*)d_in[3];
  const float* Wk   = (const float*)d_in[4];
  const float* Wv   = (const float*)d_in[5];
  const float* Wo   = (const float*)d_in[6];
  float* out = (float*)d_out;

  char* p = (char*)d_ws;
  short* Xb   = (short*)p; p += (size_t)4096 * 2048 * 2;   // reused as AO after QKV gemm
  short* Wqkv = (short*)p; p += (size_t)3072 * 2048 * 2;
  short* Wot  = (short*)p; p += (size_t)2048 * 2048 * 2;
  short* Qb   = (short*)p; p += (size_t)2 * 16 * 2048 * 128 * 2;
  short* Kb   = (short*)p; p += (size_t)2 * 4 * 2048 * 128 * 2;
  short* Vb   = (short*)p; p += (size_t)2 * 4 * 2048 * 128 * 2;
  short* AO   = Xb;

  cast_x<<<8192, 256, 0, stream>>>(hs, Xb, 2097152);
  transp_cast<<<dim3(64, 64), dim3(32, 8), 0, stream>>>(Wq, Wqkv, 2048, 2048);
  transp_cast<<<dim3(16, 64), dim3(32, 8), 0, stream>>>(Wk, Wqkv + (size_t)2048 * 2048, 2048, 512);
  transp_cast<<<dim3(16, 64), dim3(32, 8), 0, stream>>>(Wv, Wqkv + (size_t)2560 * 2048, 2048, 512);
  transp_cast<<<dim3(64, 64), dim3(32, 8), 0, stream>>>(Wo, Wot, 2048, 2048);

  gemm_bf16<1><<<dim3(32, 24), 256, 0, stream>>>(Xb, Wqkv, nullptr, Qb, Kb, Vb,
                                                 cosT, sinT, 4096, 3072, 2048);
  attn_fwd<<<dim3(32, 32), 256, 0, stream>>>(Qb, Kb, Vb, AO);
  gemm_bf16<0><<<dim3(32, 16), 256, 0, stream>>>(AO, Wot, out, nullptr, nullptr, nullptr,
                                                 nullptr, nullptr, 4096, 2048, 2048);
}

// Round 2
// 294.193 us; speedup vs baseline: 2.1176x; 2.1176x over previous
//
#include <hip/hip_runtime.h>
#include <hip/hip_bf16.h>

typedef __attribute__((ext_vector_type(8))) short bf16x8;
typedef __attribute__((ext_vector_type(4))) float f32x4;
typedef __attribute__((ext_vector_type(4))) short short4v;

__device__ __forceinline__ unsigned short f2bf(float f) {
  union { float f; unsigned u; } x; x.f = f;
  return (unsigned short)((x.u + 0x7FFFu + ((x.u >> 16) & 1u)) >> 16);
}

__device__ __forceinline__ void lds_cp16(const void* g, void* l) {
  __builtin_amdgcn_global_load_lds(
      (const __attribute__((address_space(1))) void*)g,
      (__attribute__((address_space(3))) void*)l,
      16, 0, 0);
}

// ---------------- cast fp32 -> bf16, vectorized ----------------
__global__ __launch_bounds__(256) void cast_x(const float* __restrict__ in,
                                              short* __restrict__ out, int n4) {
  int i = blockIdx.x * 256 + threadIdx.x;
  if (i >= n4) return;
  float4 v = reinterpret_cast<const float4*>(in)[i];
  short4v o;
  o.x = (short)f2bf(v.x); o.y = (short)f2bf(v.y);
  o.z = (short)f2bf(v.z); o.w = (short)f2bf(v.w);
  reinterpret_cast<short4v*>(out)[i] = o;
}

// ---------------- transpose + cast: in KxN fp32 -> out NxK bf16 ----------------
__global__ __launch_bounds__(256) void transp_cast(const float* __restrict__ in,
                                                   short* __restrict__ out,
                                                   int K, int N) {
  __shared__ float t[32][33];
  int bn = blockIdx.x * 32, bk = blockIdx.y * 32;
  int tx = threadIdx.x, ty = threadIdx.y;
  for (int i = ty; i < 32; i += 8)
    t[i][tx] = in[(size_t)(bk + i) * N + bn + tx];
  __syncthreads();
  for (int i = ty; i < 32; i += 8)
    out[(size_t)(bn + i) * K + bk + tx] = (short)f2bf(t[tx][i]);
}

// ---------------- bf16 transpose: per head [2048 pos][128 dh] -> [128 dh][2048 pos]
__global__ __launch_bounds__(256) void transp_v(const short* __restrict__ V,
                                                short* __restrict__ VTo) {
  __shared__ short t[32][34];
  const int hd = blockIdx.z;
  const int p0 = blockIdx.x * 32, d0 = blockIdx.y * 32;
  const short* src = V + (size_t)hd * 2048 * 128;
  short* dst = VTo + (size_t)hd * 2048 * 128;
  int tx = threadIdx.x, ty = threadIdx.y;
  for (int i = ty; i < 32; i += 8)
    t[i][tx] = src[(size_t)(p0 + i) * 128 + d0 + tx];
  __syncthreads();
  for (int i = ty; i < 32; i += 8)
    dst[(size_t)(d0 + i) * 2048 + p0 + tx] = t[tx][i];
}

// ---------------- GEMM: A (MxK bf16 rowmajor) @ Bt^T (Bt is NxK bf16 rowmajor)
// EPI=0: write fp32 C (MxN). EPI=1: fused RoPE epilogue -> Q/K/V bf16 head-major.
template <int EPI>
__global__ __launch_bounds__(256) void gemm_bf16(
    const short* __restrict__ A, const short* __restrict__ Bt,
    float* __restrict__ C,
    short* __restrict__ Qo, short* __restrict__ Ko, short* __restrict__ Vo,
    const float* __restrict__ cosT, const float* __restrict__ sinT,
    int M, int N, int K) {
  __shared__ __align__(16) short As[128 * 32];
  __shared__ __align__(16) short Bs[128 * 32];
  const int tid = threadIdx.x;
  const int w = tid >> 6, l = tid & 63;
  const int l15 = l & 15, l4 = l >> 4;
  const int m0 = blockIdx.x * 128, n0 = blockIdx.y * 128;

  f32x4 acc[2][8];
#pragma unroll
  for (int i = 0; i < 2; i++)
#pragma unroll
    for (int j = 0; j < 8; j++) acc[i][j] = (f32x4){0.f, 0.f, 0.f, 0.f};

  const int cA = w * 128 + l;  // 16B-chunk id; chunk c -> row c>>2, byte (c&3)*16
  for (int k0 = 0; k0 < K; k0 += 32) {
    __syncthreads();
    {
      const char* g0 = (const char*)(A + (size_t)(m0 + (cA >> 2)) * K + k0) + (cA & 3) * 16;
      const char* g1 = (const char*)(A + (size_t)(m0 + (cA >> 2) + 16) * K + k0) + (cA & 3) * 16;
      lds_cp16(g0, (char*)As + w * 2048);
      lds_cp16(g1, (char*)As + w * 2048 + 1024);
      const char* h0 = (const char*)(Bt + (size_t)(n0 + (cA >> 2)) * K + k0) + (cA & 3) * 16;
      const char* h1 = (const char*)(Bt + (size_t)(n0 + (cA >> 2) + 16) * K + k0) + (cA & 3) * 16;
      lds_cp16(h0, (char*)Bs + w * 2048);
      lds_cp16(h1, (char*)Bs + w * 2048 + 1024);
    }
    __syncthreads();
    bf16x8 a[2], b[8];
#pragma unroll
    for (int mi = 0; mi < 2; mi++)
      a[mi] = *(const bf16x8*)(As + (w * 32 + mi * 16 + l15) * 32 + l4 * 8);
#pragma unroll
    for (int ni = 0; ni < 8; ni++)
      b[ni] = *(const bf16x8*)(Bs + (ni * 16 + l15) * 32 + l4 * 8);
#pragma unroll
    for (int mi = 0; mi < 2; mi++)
#pragma unroll
      for (int ni = 0; ni < 8; ni++)
        acc[mi][ni] = __builtin_amdgcn_mfma_f32_16x16x32_bf16(a[mi], b[ni], acc[mi][ni], 0, 0, 0);
  }

  if (EPI == 0) {
#pragma unroll
    for (int mi = 0; mi < 2; mi++) {
      int row0 = m0 + w * 32 + mi * 16 + l4 * 4;
#pragma unroll
      for (int ni = 0; ni < 8; ni++) {
        int col = n0 + ni * 16 + l15;
#pragma unroll
        for (int r = 0; r < 4; r++)
          C[(size_t)(row0 + r) * N + col] = acc[mi][ni][r];
      }
    }
  } else {
    const int bn = blockIdx.y;  // one 128-wide head column per n-tile
#pragma unroll
    for (int mi = 0; mi < 2; mi++) {
#pragma unroll
      for (int r = 0; r < 4; r++) {
        int grow = m0 + w * 32 + mi * 16 + l4 * 4 + r;
        int bb = grow >> 11, pos = grow & 2047;
        if (bn < 20) {
          float c4[4], s4[4];
#pragma unroll
          for (int ni = 0; ni < 4; ni++) {
            int dh = ni * 16 + l15;  // < 64; cos/sin identical at dh and dh+64
            c4[ni] = cosT[pos * 128 + dh];
            s4[ni] = sinT[pos * 128 + dh];
          }
          short* dst;
          if (bn < 16) dst = Qo + ((size_t)(bb * 16 + bn) * 2048 + pos) * 128;
          else         dst = Ko + ((size_t)(bb * 4 + (bn - 16)) * 2048 + pos) * 128;
#pragma unroll
          for (int ni = 0; ni < 4; ni++) {
            int dh = ni * 16 + l15;
            float xlo = acc[mi][ni][r], xhi = acc[mi][ni + 4][r];
            dst[dh]      = (short)f2bf(xlo * c4[ni] - xhi * s4[ni]);
            dst[dh + 64] = (short)f2bf(xhi * c4[ni] + xlo * s4[ni]);
          }
        } else {
          short* dst = Vo + ((size_t)(bb * 4 + (bn - 20)) * 2048 + pos) * 128;
#pragma unroll
          for (int ni = 0; ni < 8; ni++)
            dst[ni * 16 + l15] = (short)f2bf(acc[mi][ni][r]);
        }
      }
    }
  }
}

// ---------------- flash attention, causal, GQA ----------------
// grid: (16, B*H); block = 4 waves. Each block processes the balanced q-tile
// pair (qt, 31-qt), 64 q-rows per tile, 16 rows/wave, KVBLK=32.
// K and V^T staged in double-buffered LDS via global_load_lds with
// pre-swizzled source addresses (swizzle = XOR on byte bits 4..6).
__global__ __launch_bounds__(256) void attn_fwd(
    const short* __restrict__ Q, const short* __restrict__ K,
    const short* __restrict__ VT, short* __restrict__ AO) {
  __shared__ __align__(16) short Ks[2][32 * 128];
  __shared__ __align__(16) short VTs[2][128 * 32];
  __shared__ __align__(16) short Pl[4][16 * 32];
  const int tid = threadIdx.x;
  const int w = tid >> 6, l = tid & 63;
  const int l15 = l & 15, l4 = l >> 4;
  const int bh = blockIdx.y;
  const int b = bh >> 4, h = bh & 15, kv = h >> 2;
  const short* Qbase = Q + (size_t)(b * 16 + h) * 2048 * 128;
  const short* Kbase = K + (size_t)(b * 4 + kv) * 2048 * 128;
  const short* VTb   = VT + (size_t)(b * 4 + kv) * 2048 * 128;

  // staging indices (per-thread invariants).
  // Ks logical (row,c): stored at byte (row*256+c*16)^((row&7)<<4).
  // chunk position idx -> row=idx>>4, cpos=idx&15, holds logical c=cpos^(row&7)
  const int rkA = tid >> 4,          ckA = (tid & 15) ^ (rkA & 7);
  const int rkB = (tid + 256) >> 4,  ckB = (tid & 15) ^ (rkB & 7);
  // VTs logical (row,c): byte (row*64+c*16)^(((row>>1)&7)<<4).
  // position idx -> row'=idx>>2,c'=idx&3; row=row'^((row'>>3)&1), c=c'^((row>>1)&3)
  const int rpA = tid >> 2,         rvA = rpA ^ ((rpA >> 3) & 1), cvA = (tid & 3) ^ ((rvA >> 1) & 3);
  const int rpB = (tid + 256) >> 2, rvB = rpB ^ ((rpB >> 3) & 1), cvB = (tid & 3) ^ ((rvB >> 1) & 3);

  const float sc_s = 0.08838834764831845f;   // 1/sqrt(128)
  const float LOG2E = 1.4426950408889634f;

  for (int qq = 0; qq < 2; qq++) {
    const int qt = qq ? (31 - blockIdx.x) : blockIdx.x;
    const int q0w = qt * 64 + w * 16;

    bf16x8 qf[4];
#pragma unroll
    for (int kb = 0; kb < 4; kb++)
      qf[kb] = *(const bf16x8*)(Qbase + (size_t)(q0w + l15) * 128 + kb * 32 + l4 * 8);

    f32x4 oacc[8];
#pragma unroll
    for (int i = 0; i < 8; i++) oacc[i] = (f32x4){0.f, 0.f, 0.f, 0.f};
    float mrow[4] = {-1e30f, -1e30f, -1e30f, -1e30f};
    float lrow[4] = {0.f, 0.f, 0.f, 0.f};

    const int ntiles = 2 * qt + 2;

    __syncthreads();  // prior q-tile's LDS reads complete before restaging
    // stage tile 0 into buffer 0
    {
      lds_cp16(Kbase + (size_t)rkA * 128 + ckA * 8, (char*)Ks[0] + w * 1024);
      lds_cp16(Kbase + (size_t)rkB * 128 + ckB * 8, (char*)Ks[0] + 4096 + w * 1024);
      lds_cp16(VTb + (size_t)rvA * 2048 + cvA * 8,  (char*)VTs[0] + w * 1024);
      lds_cp16(VTb + (size_t)rvB * 2048 + cvB * 8,  (char*)VTs[0] + 4096 + w * 1024);
    }

    for (int nt = 0; nt < ntiles; nt++) {
      const int k0 = nt * 32, buf = nt & 1;
      __syncthreads();  // drains own vmcnt -> tile nt resident for all waves
      if (nt + 1 < ntiles) {
        const int kn = k0 + 32, bn = buf ^ 1;
        lds_cp16(Kbase + (size_t)(kn + rkA) * 128 + ckA * 8, (char*)Ks[bn] + w * 1024);
        lds_cp16(Kbase + (size_t)(kn + rkB) * 128 + ckB * 8, (char*)Ks[bn] + 4096 + w * 1024);
        lds_cp16(VTb + (size_t)rvA * 2048 + kn + cvA * 8,    (char*)VTs[bn] + w * 1024);
        lds_cp16(VTb + (size_t)rvB * 2048 + kn + cvB * 8,    (char*)VTs[bn] + 4096 + w * 1024);
      }

      // S = Q @ K^T  (16 q x 32 keys per wave), K from swizzled LDS
      f32x4 sa[2];
      sa[0] = (f32x4){0.f, 0.f, 0.f, 0.f};
      sa[1] = (f32x4){0.f, 0.f, 0.f, 0.f};
#pragma unroll
      for (int kg = 0; kg < 2; kg++) {
        const int row = kg * 16 + l15;
        const int swz = (row & 7) << 4;
#pragma unroll
        for (int kb = 0; kb < 4; kb++) {
          const char* kp = (const char*)Ks[buf] + ((row * 256 + kb * 64 + l4 * 16) ^ swz);
          sa[kg] = __builtin_amdgcn_mfma_f32_16x16x32_bf16(qf[kb], *(const bf16x8*)kp, sa[kg], 0, 0, 0);
        }
      }

      // online softmax; C-layout row = l4*4+r, col(key) = kg*16+l15
      float p[2][4], tilem[4];
#pragma unroll
      for (int r = 0; r < 4; r++) {
        int qrow = q0w + l4 * 4 + r;
        float s0 = sa[0][r] * sc_s; if (k0 + l15 > qrow)      s0 = -1e30f;
        float s1 = sa[1][r] * sc_s; if (k0 + 16 + l15 > qrow) s1 = -1e30f;
        p[0][r] = s0; p[1][r] = s1;
        float t = fmaxf(s0, s1);
        t = fmaxf(t, __shfl_xor(t, 1));
        t = fmaxf(t, __shfl_xor(t, 2));
        t = fmaxf(t, __shfl_xor(t, 4));
        t = fmaxf(t, __shfl_xor(t, 8));
        tilem[r] = t;
      }
#pragma unroll
      for (int r = 0; r < 4; r++) {
        float newm = fmaxf(mrow[r], tilem[r]);
        float scal = exp2f((mrow[r] - newm) * LOG2E);
        mrow[r] = newm;
        float p0 = exp2f((p[0][r] - newm) * LOG2E);
        float p1 = exp2f((p[1][r] - newm) * LOG2E);
        p[0][r] = p0; p[1][r] = p1;
        float ts = p0 + p1;
        ts += __shfl_xor(ts, 1);
        ts += __shfl_xor(ts, 2);
        ts += __shfl_xor(ts, 4);
        ts += __shfl_xor(ts, 8);
        lrow[r] = lrow[r] * scal + ts;
#pragma unroll
        for (int nb = 0; nb < 8; nb++) oacc[nb][r] *= scal;
      }

      // P: C-layout -> A-layout via per-wave LDS (swizzled rows)
#pragma unroll
      for (int r = 0; r < 4; r++) {
        const int rw = l4 * 4 + r;
        const int swz = ((rw >> 1) & 7) << 4;
        *(short*)((char*)Pl[w] + ((rw * 64 + l15 * 2) ^ swz))      = (short)f2bf(p[0][r]);
        *(short*)((char*)Pl[w] + ((rw * 64 + 32 + l15 * 2) ^ swz)) = (short)f2bf(p[1][r]);
      }
      asm volatile("s_waitcnt lgkmcnt(0)" ::: "memory");
      bf16x8 pf = *(const bf16x8*)((const char*)Pl[w] + ((l15 * 64 + l4 * 16) ^ (((l15 >> 1) & 7) << 4)));
#pragma unroll
      for (int nb = 0; nb < 8; nb++) {
        const int row = nb * 16 + l15;
        const char* vp = (const char*)VTs[buf] + ((row * 64 + l4 * 16) ^ (((row >> 1) & 7) << 4));
        oacc[nb] = __builtin_amdgcn_mfma_f32_16x16x32_bf16(pf, *(const bf16x8*)vp, oacc[nb], 0, 0, 0);
      }
    }

    // epilogue: normalize, write bf16 AO [B][L][H*Dh]
#pragma unroll
    for (int r = 0; r < 4; r++) {
      float inv = 1.0f / lrow[r];
      size_t rowb = ((size_t)b * 2048 + q0w + l4 * 4 + r) * 2048 + h * 128;
#pragma unroll
      for (int nb = 0; nb < 8; nb++)
        AO[rowb + nb * 16 + l15] = (short)f2bf(oacc[nb][r] * inv);
    }
  }
}

extern "C" void kernel_launch(void* const* d_in, const int* in_sizes, int n_in,
                              void* d_out, int out_size, void* d_ws, size_t ws_size,
                              hipStream_t stream) {
  const float* hs   = (const float*)d_in[0];
  const float* cosT = (const float*)d_in[1];
  const float* sinT = (const float*)d_in[2];
  const float* Wq   = (const float*)d_in[3];
  const float* Wk   = (const float*)d_in[4];
  const float* Wv   = (const float*)d_in[5];
  const float* Wo   = (const float*)d_in[6];
  float* out = (float*)d_out;

  char* p = (char*)d_ws;
  short* Xb   = (short*)p; p += (size_t)4096 * 2048 * 2;   // reused as AO after QKV gemm
  short* Wqkv = (short*)p; p += (size_t)3072 * 2048 * 2;
  short* Wot  = (short*)p; p += (size_t)2048 * 2048 * 2;
  short* Qb   = (short*)p; p += (size_t)2 * 16 * 2048 * 128 * 2;
  short* Kb   = (short*)p; p += (size_t)2 * 4 * 2048 * 128 * 2;
  short* Vb   = (short*)p; p += (size_t)2 * 4 * 2048 * 128 * 2;
  short* VTb  = (short*)p; p += (size_t)2 * 4 * 2048 * 128 * 2;
  short* AO   = Xb;

  cast_x<<<8192, 256, 0, stream>>>(hs, Xb, 2097152);
  transp_cast<<<dim3(64, 64), dim3(32, 8), 0, stream>>>(Wq, Wqkv, 2048, 2048);
  transp_cast<<<dim3(16, 64), dim3(32, 8), 0, stream>>>(Wk, Wqkv + (size_t)2048 * 2048, 2048, 512);
  transp_cast<<<dim3(16, 64), dim3(32, 8), 0, stream>>>(Wv, Wqkv + (size_t)2560 * 2048, 2048, 512);
  transp_cast<<<dim3(64, 64), dim3(32, 8), 0, stream>>>(Wo, Wot, 2048, 2048);

  gemm_bf16<1><<<dim3(32, 24), 256, 0, stream>>>(Xb, Wqkv, nullptr, Qb, Kb, Vb,
                                                 cosT, sinT, 4096, 3072, 2048);
  transp_v<<<dim3(64, 4, 8), dim3(32, 8), 0, stream>>>(Vb, VTb);
  attn_fwd<<<dim3(16, 32), 256, 0, stream>>>(Qb, Kb, VTb, AO);
  gemm_bf16<0><<<dim3(32, 16), 256, 0, stream>>>(AO, Wot, out, nullptr, nullptr, nullptr,
                                                 nullptr, nullptr, 4096, 2048, 2048);
}